// Round 15
// baseline (80.358 us; speedup 1.0000x reference)
//
#include <hip/hip_runtime.h>

#define BB 4
#define CC 16
#define HH 256
#define WW 512
#define NHD 8
#define DD 32

typedef __attribute__((ext_vector_type(8))) short s8b;        // 8 bf16 (4 VGPRs)
typedef __attribute__((ext_vector_type(4))) float f32x4;
typedef __attribute__((ext_vector_type(4))) unsigned int u32x4;
typedef __attribute__((ext_vector_type(2))) int i32x2;

__device__ inline unsigned cvtpk(float a, float b) {          // (lo=a, hi=b) bf16 RNE
    unsigned r;
    asm("v_cvt_pk_bf16_f32 %0, %1, %2" : "=v"(r) : "v"(a), "v"(b));
    return r;
}
__device__ inline f32x4 mfma16(u32x4 a, u32x4 b, f32x4 c) {
    return __builtin_amdgcn_mfma_f32_16x16x32_bf16(
        __builtin_bit_cast(s8b, a), __builtin_bit_cast(s8b, b), c, 0, 0, 0);
}

// ---------------------------------------------------------------------------
// Setup: build bf16 hi/lo weight A-fragments for all 4 convs (q,k,v,o).
// ---------------------------------------------------------------------------
__global__ __launch_bounds__(64)
void wsetup_kernel(const float* __restrict__ w0, const float* __restrict__ w1,
                   const float* __restrict__ w2, const float* __restrict__ w3,
                   unsigned* __restrict__ wfrag)
{
    const int lane = threadIdx.x;
    const int cv = blockIdx.x;
    const float* wg[4] = {w0, w1, w2, w3};
    const int r = lane & 15, g = lane >> 4;
    const int ci0 = (g & 1) * 8;
    #pragma unroll
    for (int kg = 0; kg < 5; ++kg) {
        int tap = 2*kg + (g >> 1);
        unsigned hi[4], lo[4];
        #pragma unroll
        for (int j = 0; j < 4; ++j) {
            float e0 = 0.f, e1 = 0.f;
            if (tap < 9) {
                e0 = wg[cv][(r*CC + ci0 + 2*j    )*9 + tap];
                e1 = wg[cv][(r*CC + ci0 + 2*j + 1)*9 + tap];
            }
            unsigned h = cvtpk(e0, e1);
            float f0 = __builtin_bit_cast(float, h << 16);
            float f1 = __builtin_bit_cast(float, h & 0xffff0000u);
            hi[j] = h;
            lo[j] = cvtpk(e0 - f0, e1 - f1);
        }
        *(u32x4*)(wfrag + (size_t)(((0*4 + cv)*5 + kg)*64 + lane)*4) =
            (u32x4){hi[0], hi[1], hi[2], hi[3]};
        *(u32x4*)(wfrag + (size_t)(((1*4 + cv)*5 + kg)*64 + lane)*4) =
            (u32x4){lo[0], lo[1], lo[2], lo[3]};
    }
}

// ---------------------------------------------------------------------------
// bf16-MFMA implicit-GEMM 3x3 conv.
// INMODE: 0 = fp32 planar -> TWO-PHASE stage: Phase A reads 2 channel-planes
//             per raw element (coalesced over w), cvtpk -> channel-paired raw
//             LDS tile [8cp][18][34]; Phase B per-pixel 8 paired u32 reads
//             (no v_perm) -> xs.  (replaces the old xpack pre-pass)
//         1 = h-paired bf16 planar [c][h/2][w] -> coalesced raw tile
//             [16][10][34], then per-pixel reads + v_perm.
// NTERM=1: wh*xh only; NTERM=2: +wl*xh.
// OUT_PAIRED: 3 outputs bf16 h-paired; else fp32 planar.
// kscale: extra output scale on cv==1 (folds softmax scale into k).
// ---------------------------------------------------------------------------
template<int NC, int CVB, int INMODE, bool OUT_PAIRED, int NTERM>
__global__ __launch_bounds__(256)
void conv_mfma_kernel(const void* __restrict__ xin,
                      const unsigned* __restrict__ wfrag,
                      const float* __restrict__ b0, const float* __restrict__ b1,
                      const float* __restrict__ b2,
                      unsigned* __restrict__ o0, unsigned* __restrict__ o1,
                      unsigned* __restrict__ o2, float* __restrict__ of,
                      float kscale)
{
    constexpr int LC2 = 34, NPX = 18*34;                  // 612 pixels w/ halo
    __shared__ __align__(16) unsigned char xs[NPX*32];
    __shared__ unsigned rawv[(INMODE == 1) ? 16*10*34 : 8*18*34];

    const int tid = threadIdx.x;
    const int bx = blockIdx.x, by = blockIdx.y, bz = blockIdx.z;
    const int lane = tid & 63, wid = tid >> 6;
    const int g = lane >> 4, r = lane & 15;

    u32x4 wh[NC][5], wl[NC][5];
    #pragma unroll
    for (int cv = 0; cv < NC; ++cv)
        #pragma unroll
        for (int kg = 0; kg < 5; ++kg) {
            wh[cv][kg] = *(const u32x4*)(wfrag + (size_t)(((CVB+cv)*5 + kg)*64 + lane)*4);
            if constexpr (NTERM >= 2)
                wl[cv][kg] = *(const u32x4*)(wfrag + (size_t)(((4+CVB+cv)*5 + kg)*64 + lane)*4);
        }
    const float* bg[3] = {b0, b1, b2};
    f32x4 bias[NC];
    #pragma unroll
    for (int cv = 0; cv < NC; ++cv) bias[cv] = *(const f32x4*)(bg[cv] + 4*g);

    const int row0 = by*16 - 1, col0 = bx*32 - 1;

    if constexpr (INMODE == 0) {
        // Phase A: channel-paired raw tile, coalesced fp32 loads
        const float* xb = (const float*)xin + (size_t)bz*CC*HH*WW;
        for (int idx = tid; idx < 8*18*34; idx += 256) {
            int cp  = idx / 612;
            int rem = idx - cp*612;
            int hr  = rem / 34;
            int wr  = rem - hr*34;
            int gr = row0 + hr; gr = gr < 0 ? 0 : (gr > HH-1 ? HH-1 : gr);
            int gc = col0 + wr; gc = gc < 0 ? 0 : (gc > WW-1 ? WW-1 : gc);
            const float* px = xb + (size_t)(2*cp)*HH*WW + (size_t)gr*WW + gc;
            rawv[idx] = cvtpk(px[0], px[(size_t)HH*WW]);
        }
        __syncthreads();
        // Phase B: per-pixel paired reads -> xs (zero OOB)
        for (int idx = tid; idx < NPX; idx += 256) {
            int rr = idx / LC2, cc2 = idx - rr*LC2;
            int gr = row0 + rr, gc = col0 + cc2;
            bool ok = (gr >= 0) & (gr < HH) & (gc >= 0) & (gc < WW);
            unsigned hi[8];
            #pragma unroll
            for (int cp = 0; cp < 8; ++cp)
                hi[cp] = ok ? rawv[cp*612 + rr*34 + cc2] : 0u;
            unsigned base = (unsigned)idx*32, m = ((unsigned)idx & 4) << 2;
            *(u32x4*)(xs + base + (( 0u) ^ m)) = (u32x4){hi[0], hi[1], hi[2], hi[3]};
            *(u32x4*)(xs + base + ((16u) ^ m)) = (u32x4){hi[4], hi[5], hi[6], hi[7]};
        }
    } else {
        // Phase A: coalesced raw stage of hp-rows [8by-1 .. 8by+8] x 34 cols
        const unsigned* xb = (const unsigned*)xin + (size_t)bz*CC*(HH/2)*WW;
        const int hpbase = 8*by - 1;
        for (int idx = tid; idx < 16*10*34; idx += 256) {
            int c   = idx / 340;
            int rem = idx - c*340;
            int hpr = rem / 34;
            int wr  = rem - hpr*34;
            int hpg = hpbase + hpr; hpg = hpg < 0 ? 0 : (hpg > 127 ? 127 : hpg);
            int gcc = col0 + wr;    gcc = gcc < 0 ? 0 : (gcc > WW-1 ? WW-1 : gcc);
            rawv[idx] = xb[(size_t)c*(HH/2)*WW + (size_t)hpg*WW + gcc];
        }
        __syncthreads();
        // Phase B: per-pixel LDS reads + v_perm -> xs channel-last
        for (int idx = tid; idx < NPX; idx += 256) {
            int rr = idx / LC2, cc2 = idx - rr*LC2;
            int gr = row0 + rr;
            bool ok = (gr >= 0) & (gr < HH) & ((col0 + cc2) >= 0) & ((col0 + cc2) < WW);
            int grc = gr < 0 ? 0 : (gr > HH-1 ? HH-1 : gr);
            int hl  = (grc >> 1) - hpbase;        // in [0,9]
            const unsigned sel = (grc & 1) ? 0x07060302u : 0x05040100u;
            unsigned wv[16];
            #pragma unroll
            for (int c8 = 0; c8 < 16; ++c8)
                wv[c8] = ok ? rawv[c8*340 + hl*34 + cc2] : 0u;
            unsigned hi[8];
            #pragma unroll
            for (int p = 0; p < 8; ++p)
                hi[p] = __builtin_amdgcn_perm(wv[2*p+1], wv[2*p], sel);
            unsigned base = (unsigned)idx*32, m = ((unsigned)idx & 4) << 2;
            *(u32x4*)(xs + base + (( 0u) ^ m)) = (u32x4){hi[0], hi[1], hi[2], hi[3]};
            *(u32x4*)(xs + base + ((16u) ^ m)) = (u32x4){hi[4], hi[5], hi[6], hi[7]};
        }
    }
    __syncthreads();

    int pk_base[5];
    #pragma unroll
    for (int kg = 0; kg < 5; ++kg) {
        int tap = 2*kg + (g >> 1);
        if (tap > 8) tap = 8;
        pk_base[kg] = (tap/3)*LC2 + (tap%3) + r;
    }
    const unsigned sh = (unsigned)(g & 1) << 4;

    auto tile = [&](int hr, int wt, f32x4* acc) {
        const int tb = hr*LC2 + wt*16;
        #pragma unroll
        for (int kg = 0; kg < 5; ++kg) {
            int px = tb + pk_base[kg];
            unsigned b_ = (unsigned)px*32, m = ((unsigned)px & 4) << 2;
            u32x4 Bh = *(const u32x4*)(xs + b_ + (sh ^ m));
            #pragma unroll
            for (int cv = 0; cv < NC; ++cv) {
                acc[cv] = mfma16(wh[cv][kg], Bh, acc[cv]);
                if constexpr (NTERM >= 2)
                    acc[cv] = mfma16(wl[cv][kg], Bh, acc[cv]);
            }
        }
    };

    #pragma unroll 1
    for (int hp = 0; hp < 2; ++hp) {
        const int hrE = 4*wid + 2*hp;
        #pragma unroll 1
        for (int wt = 0; wt < 2; ++wt) {
            const int col = bx*32 + wt*16 + r;
            if constexpr (OUT_PAIRED) {
                f32x4 aE[NC];
                #pragma unroll
                for (int cv = 0; cv < NC; ++cv) aE[cv] = (f32x4){0.f,0.f,0.f,0.f};
                tile(hrE, wt, aE);
                unsigned Ep[NC][2];
                #pragma unroll
                for (int cv = 0; cv < NC; ++cv) {
                    const float sc = (cv == 1) ? kscale : 1.0f;
                    Ep[cv][0] = cvtpk((aE[cv][0] + bias[cv][0])*sc, (aE[cv][1] + bias[cv][1])*sc);
                    Ep[cv][1] = cvtpk((aE[cv][2] + bias[cv][2])*sc, (aE[cv][3] + bias[cv][3])*sc);
                }
                f32x4 aO[NC];
                #pragma unroll
                for (int cv = 0; cv < NC; ++cv) aO[cv] = (f32x4){0.f,0.f,0.f,0.f};
                tile(hrE + 1, wt, aO);
                const int hpix = by*8 + 2*wid + hp;
                #pragma unroll
                for (int cv = 0; cv < NC; ++cv) {
                    const float sc = (cv == 1) ? kscale : 1.0f;
                    unsigned Op0 = cvtpk((aO[cv][0] + bias[cv][0])*sc, (aO[cv][1] + bias[cv][1])*sc);
                    unsigned Op1 = cvtpk((aO[cv][2] + bias[cv][2])*sc, (aO[cv][3] + bias[cv][3])*sc);
                    unsigned wd[4] = {
                        __builtin_amdgcn_perm(Op0, Ep[cv][0], 0x05040100u),
                        __builtin_amdgcn_perm(Op0, Ep[cv][0], 0x07060302u),
                        __builtin_amdgcn_perm(Op1, Ep[cv][1], 0x05040100u),
                        __builtin_amdgcn_perm(Op1, Ep[cv][1], 0x07060302u) };
                    unsigned* op = (cv == 0) ? o0 : (cv == 1) ? o1 : o2;
                    #pragma unroll
                    for (int reg = 0; reg < 4; ++reg)
                        op[((size_t)(bz*CC + 4*g + reg)*(HH/2) + hpix)*WW + col] = wd[reg];
                }
            } else {
                #pragma unroll 1
                for (int e = 0; e < 2; ++e) {
                    f32x4 a0[1] = {(f32x4){0.f,0.f,0.f,0.f}};
                    tile(hrE + e, wt, a0);
                    const int h = by*16 + hrE + e;
                    #pragma unroll
                    for (int reg = 0; reg < 4; ++reg)
                        of[((size_t)(bz*CC + 4*g + reg)*HH + h)*WW + col] =
                            a0[0][reg] + bias[0][reg];
                }
            }
        }
    }
}

// ---------------------------------------------------------------------------
// bf16 MFMA flash attention (best-measured config): swapped-operand +
// permlane P-transpose, one-shot 64 KiB K/V stage, qi=4, ones-row MFMA for l.
// Output written as h-paired bf16 u32 [c][h/2][w] (feeds conv1 directly).
// ---------------------------------------------------------------------------
__global__ __launch_bounds__(512)
void attn_mfma_kernel(const unsigned* __restrict__ q,
                      const unsigned* __restrict__ k,
                      const unsigned* __restrict__ v,
                      unsigned* __restrict__ apk)
{
    __shared__ __align__(16) unsigned char Kl[WW*DD*2];      // 32 KiB
    __shared__ __align__(16) unsigned char Vl[DD*WW*2];      // 32 KiB

    const int s  = blockIdx.x;
    const int n  = s & (NHD-1);
    const int bc = s >> 3;
    const int pbase = (bc*(HH/2) + n*(DD/2)) * WW;           // u32 elements
    const unsigned* qg = q + pbase;
    const unsigned* kg = k + pbase;
    const unsigned* vg = v + pbase;
    unsigned* ag = apk + pbase;

    const int tid = threadIdx.x;

    // --- stage K: thread t -> key = t; 16 d-pair words, native layout ---
    {
        const int key = tid;
        unsigned pk[16];
        #pragma unroll
        for (int dp = 0; dp < 16; ++dp) pk[dp] = kg[(size_t)dp*WW + key];
        #pragma unroll
        for (int j = 0; j < 4; ++j) {
            unsigned off = (unsigned)(key*64 + j*16) ^ ((unsigned)(key&7) << 4);
            *(u32x4*)(Kl + off) = (u32x4){pk[4*j], pk[4*j+1], pk[4*j+2], pk[4*j+3]};
        }
    }
    // --- stage V: unzip d-pairs -> Vl[d][key-slots] via v_perm.
    // Slot order per 16-key chunk applies quad perm [0,2,1,3]: the two b128
    // writes carry word sets {P0,P1,P4,P5} and {P2,P3,P6,P7}. ---
    {
        const int dp = tid >> 5;                  // 0..15
        const int k0 = (tid & 31) * 16;
        unsigned rowE[8], rowO[8];
        #pragma unroll
        for (int j = 0; j < 4; ++j) {
            u32x4 U = *(const u32x4*)(vg + (size_t)dp*WW + k0 + 4*j);
            rowE[2*j  ] = __builtin_amdgcn_perm(U[1], U[0], 0x05040100u);
            rowE[2*j+1] = __builtin_amdgcn_perm(U[3], U[2], 0x05040100u);
            rowO[2*j  ] = __builtin_amdgcn_perm(U[1], U[0], 0x07060302u);
            rowO[2*j+1] = __builtin_amdgcn_perm(U[3], U[2], 0x07060302u);
        }
        const int d0 = 2*dp, d1 = 2*dp + 1;
        const unsigned bE = (unsigned)(d0*1024 + k0*2);
        const unsigned bO = (unsigned)(d1*1024 + k0*2);
        const unsigned mE = ((unsigned)d0 & 7u) << 4;
        const unsigned mO = ((unsigned)d1 & 7u) << 4;
        *(u32x4*)(Vl + ((bE     ) ^ mE)) = (u32x4){rowE[0], rowE[1], rowE[4], rowE[5]};
        *(u32x4*)(Vl + ((bE + 16) ^ mE)) = (u32x4){rowE[2], rowE[3], rowE[6], rowE[7]};
        *(u32x4*)(Vl + ((bO     ) ^ mO)) = (u32x4){rowO[0], rowO[1], rowO[4], rowO[5]};
        *(u32x4*)(Vl + ((bO + 16) ^ mO)) = (u32x4){rowO[2], rowO[3], rowO[6], rowO[7]};
    }

    const int wid  = tid >> 6;
    const int lane = tid & 63;
    const int g = lane >> 4;
    const int r = lane & 15;
    const int w0 = wid * 64;

    // --- per-wave Q B-fragments (col = query r, k = d octet 8g..8g+7) ---
    u32x4 qf[4];
    #pragma unroll
    for (int rf = 0; rf < 4; ++rf) {
        const int row = w0 + rf*16 + r;
        unsigned pq[4];
        #pragma unroll
        for (int jj = 0; jj < 4; ++jj)
            pq[jj] = qg[(size_t)(4*g + jj)*WW + row];
        qf[rf] = (u32x4){pq[0], pq[1], pq[2], pq[3]};
    }

    __syncthreads();   // K/V staged

    // ones A-fragment (row 0 = 1.0) for l = sum_k P^T
    const u32x4 vones = (r == 0)
        ? (u32x4){0x3F803F80u, 0x3F803F80u, 0x3F803F80u, 0x3F803F80u}
        : (u32x4){0u, 0u, 0u, 0u};

    f32x4 oacc[4][2];
    f32x4 lacc[4];
    #pragma unroll
    for (int qi = 0; qi < 4; ++qi) {
        oacc[qi][0] = (f32x4){0.f,0.f,0.f,0.f};
        oacc[qi][1] = (f32x4){0.f,0.f,0.f,0.f};
        lacc[qi]    = (f32x4){0.f,0.f,0.f,0.f};
    }

    #pragma unroll 1
    for (int j0 = 0; j0 < WW; j0 += 32) {
        u32x4 kf[2];
        #pragma unroll
        for (int cf = 0; cf < 2; ++cf) {
            const int key = j0 + cf*16 + r;
            unsigned off = (unsigned)(key*64 + g*16) ^ ((unsigned)(key&7) << 4);
            kf[cf] = *(const u32x4*)(Kl + off);
        }
        u32x4 vf[2];
        #pragma unroll
        for (int cfd = 0; cfd < 2; ++cfd) {
            const int d = r + 16*cfd;
            unsigned off = (unsigned)(d*1024 + (j0 + 8*g)*2) ^ ((unsigned)(d&7) << 4);
            vf[cfd] = *(const u32x4*)(Vl + off);
        }

        f32x4 sacc[4][2];
        #pragma unroll
        for (int qi = 0; qi < 4; ++qi) {
            sacc[qi][0] = mfma16(kf[0], qf[qi], (f32x4){0.f,0.f,0.f,0.f});
            sacc[qi][1] = mfma16(kf[1], qf[qi], (f32x4){0.f,0.f,0.f,0.f});
        }

        #pragma unroll
        for (int qi = 0; qi < 4; ++qi) {
            float p0 = __builtin_amdgcn_exp2f(sacc[qi][0][0]);
            float p1 = __builtin_amdgcn_exp2f(sacc[qi][0][1]);
            float p2 = __builtin_amdgcn_exp2f(sacc[qi][0][2]);
            float p3 = __builtin_amdgcn_exp2f(sacc[qi][0][3]);
            float p4 = __builtin_amdgcn_exp2f(sacc[qi][1][0]);
            float p5 = __builtin_amdgcn_exp2f(sacc[qi][1][1]);
            float p6 = __builtin_amdgcn_exp2f(sacc[qi][1][2]);
            float p7 = __builtin_amdgcn_exp2f(sacc[qi][1][3]);
            unsigned Aw = cvtpk(p0, p1);   // keys (4g,   4g+1)
            unsigned Bw = cvtpk(p2, p3);   // keys (4g+2, 4g+3)
            unsigned Cw = cvtpk(p4, p5);   // keys (16+4g, 16+4g+1)
            unsigned Dw = cvtpk(p6, p7);   // keys (16+4g+2, 16+4g+3)
            i32x2 w02 = __builtin_amdgcn_permlane32_swap((int)Aw, (int)Cw, false, false);
            i32x2 w13 = __builtin_amdgcn_permlane32_swap((int)Bw, (int)Dw, false, false);
            u32x4 pa = (u32x4){ (unsigned)w02[0], (unsigned)w13[0],
                                (unsigned)w02[1], (unsigned)w13[1] };
            oacc[qi][0] = mfma16(vf[0], pa, oacc[qi][0]);
            oacc[qi][1] = mfma16(vf[1], pa, oacc[qi][1]);
            lacc[qi]    = mfma16(vones, pa, lacc[qi]);
        }
    }

    // normalize + store h-paired bf16: regs 0/1 and 2/3 are consecutive d.
    #pragma unroll
    for (int qi = 0; qi < 4; ++qi) {
        float l = __shfl(lacc[qi][0], r);     // lane r (g=0,reg0) holds col-r sum
        float inv = 1.0f / l;
        const int qcol = w0 + qi*16 + r;
        #pragma unroll
        for (int cfd = 0; cfd < 2; ++cfd) {
            const int dpair = 8*cfd + 2*g;    // d = 16cfd + 4g + reg
            unsigned P0 = cvtpk(oacc[qi][cfd][0]*inv, oacc[qi][cfd][1]*inv);
            unsigned P1 = cvtpk(oacc[qi][cfd][2]*inv, oacc[qi][cfd][3]*inv);
            ag[(size_t)(dpair    )*WW + qcol] = P0;
            ag[(size_t)(dpair + 1)*WW + qcol] = P1;
        }
    }
}

extern "C" void kernel_launch(void* const* d_in, const int* in_sizes, int n_in,
                              void* d_out, int out_size, void* d_ws, size_t ws_size,
                              hipStream_t stream) {
    (void)in_sizes; (void)n_in; (void)out_size; (void)ws_size;
    const float* x  = (const float*)d_in[0];
    const float* wq = (const float*)d_in[1];
    const float* bq = (const float*)d_in[2];
    const float* wk = (const float*)d_in[3];
    const float* bk = (const float*)d_in[4];
    const float* wv = (const float*)d_in[5];
    const float* bv = (const float*)d_in[6];
    const float* wo = (const float*)d_in[7];
    const float* bo = (const float*)d_in[8];
    float* out = (float*)d_out;

    const float SC = 0.0625f * 1.44269504088896340736f;  // 1/sqrt(256) * log2(e)

    const size_t S = (size_t)BB*CC*HH*WW;          // 8388608
    unsigned* apk  = (unsigned*)d_ws;              // S/2 u32 (h-paired bf16)
    unsigned* qpk  = apk + S/2;
    unsigned* kpk  = qpk + S/2;
    unsigned* vpk  = kpk + S/2;
    unsigned* wfrag = vpk + S/2;                   // 10240 u32

    wsetup_kernel<<<dim3(4), 64, 0, stream>>>(wq, wk, wv, wo, wfrag);
    dim3 cgrid(WW/32, HH/16, BB);                  // (16,16,4)
    conv_mfma_kernel<3, 0, 0, true, 1><<<cgrid, 256, 0, stream>>>(
        x, wfrag, bq, bk, bv, qpk, kpk, vpk, nullptr, SC);
    attn_mfma_kernel<<<dim3(512), 512, 0, stream>>>(qpk, kpk, vpk, apk);
    conv_mfma_kernel<1, 3, 1, false, 2><<<cgrid, 256, 0, stream>>>(
        apk, wfrag, bo, bo, bo, nullptr, nullptr, nullptr, out, 1.0f);
}

// Round 16
// 74.855 us; speedup vs baseline: 1.0735x; 1.0735x over previous
//
#include <hip/hip_runtime.h>

#define BB 4
#define CC 16
#define HH 256
#define WW 512
#define NHD 8
#define DD 32

typedef __attribute__((ext_vector_type(8))) short s8b;        // 8 bf16 (4 VGPRs)
typedef __attribute__((ext_vector_type(4))) float f32x4;
typedef __attribute__((ext_vector_type(4))) unsigned int u32x4;
typedef __attribute__((ext_vector_type(2))) int i32x2;

__device__ inline unsigned cvtpk(float a, float b) {          // (lo=a, hi=b) bf16 RNE
    unsigned r;
    asm("v_cvt_pk_bf16_f32 %0, %1, %2" : "=v"(r) : "v"(a), "v"(b));
    return r;
}
__device__ inline f32x4 mfma16(u32x4 a, u32x4 b, f32x4 c) {
    return __builtin_amdgcn_mfma_f32_16x16x32_bf16(
        __builtin_bit_cast(s8b, a), __builtin_bit_cast(s8b, b), c, 0, 0, 0);
}

// ---------------------------------------------------------------------------
// xpack (+ merged wsetup): z<BB planes: x fp32 planar -> xcl bf16 channel-last
// [b][h][w][8 u32]. z==BB plane: 4 blocks build weight A-fragments (hi/lo)
// for the 4 convs into wfrag; remaining blocks return immediately.
// ---------------------------------------------------------------------------
__global__ __launch_bounds__(256)
void xpack_kernel(const float* __restrict__ x, unsigned* __restrict__ xcl,
                  const float* __restrict__ w0, const float* __restrict__ w1,
                  const float* __restrict__ w2, const float* __restrict__ w3,
                  unsigned* __restrict__ wfrag)
{
    __shared__ float xsf[8][16][68];
    const int tid = threadIdx.x;
    const int bx = blockIdx.x, by = blockIdx.y, bz = blockIdx.z;

    if (bz == BB) {                       // -------- wsetup plane --------
        if (bx >= 4 || by != 0 || tid >= 64) return;
        const int lane = tid;
        const int cv = bx;
        const float* wg[4] = {w0, w1, w2, w3};
        const int r = lane & 15, g = lane >> 4;
        const int ci0 = (g & 1) * 8;
        #pragma unroll
        for (int kg = 0; kg < 5; ++kg) {
            int tap = 2*kg + (g >> 1);
            unsigned hi[4], lo[4];
            #pragma unroll
            for (int j = 0; j < 4; ++j) {
                float e0 = 0.f, e1 = 0.f;
                if (tap < 9) {
                    e0 = wg[cv][(r*CC + ci0 + 2*j    )*9 + tap];
                    e1 = wg[cv][(r*CC + ci0 + 2*j + 1)*9 + tap];
                }
                unsigned h = cvtpk(e0, e1);
                float f0 = __builtin_bit_cast(float, h << 16);
                float f1 = __builtin_bit_cast(float, h & 0xffff0000u);
                hi[j] = h;
                lo[j] = cvtpk(e0 - f0, e1 - f1);
            }
            *(u32x4*)(wfrag + (size_t)(((0*4 + cv)*5 + kg)*64 + lane)*4) =
                (u32x4){hi[0], hi[1], hi[2], hi[3]};
            *(u32x4*)(wfrag + (size_t)(((1*4 + cv)*5 + kg)*64 + lane)*4) =
                (u32x4){lo[0], lo[1], lo[2], lo[3]};
        }
        return;
    }

    const float* xb = x + (size_t)bz*CC*HH*WW + (size_t)(by*8)*WW + bx*64;

    #pragma unroll
    for (int k = 0; k < 8; ++k) {
        int idx = tid + k*256;            // (ci, hh, q)
        int ci  = idx >> 7;
        int rem = idx & 127;
        int hh  = rem >> 4;
        int qq  = rem & 15;
        f32x4 v = *(const f32x4*)(xb + (size_t)ci*HH*WW + (size_t)hh*WW + qq*4);
        *(f32x4*)&xsf[hh][ci][qq*4] = v;
    }
    __syncthreads();

    #pragma unroll
    for (int k = 0; k < 2; ++k) {
        int p  = tid + k*256;             // pixel in chunk
        int hh = p >> 6, ww = p & 63;
        unsigned pk[8];
        #pragma unroll
        for (int q = 0; q < 8; ++q)
            pk[q] = cvtpk(xsf[hh][2*q][ww], xsf[hh][2*q+1][ww]);
        unsigned* op = xcl + ((size_t)(bz*HH + by*8 + hh)*WW + bx*64 + ww)*8;
        *(u32x4*)(op    ) = (u32x4){pk[0], pk[1], pk[2], pk[3]};
        *(u32x4*)(op + 4) = (u32x4){pk[4], pk[5], pk[6], pk[7]};
    }
}

// ---------------------------------------------------------------------------
// bf16-MFMA implicit-GEMM 3x3 conv.
// INMODE: 1 = h-paired bf16 planar [c][h/2][w] -> TWO-PHASE stage:
//             coalesced raw tile [16][10][34] in LDS, then per-pixel
//             LDS reads + v_perm into xs (no strided global gathers).
//         2 = channel-last bf16 [h][w][8u32] (from xpack; 2 b128 loads/px).
// NTERM=1: wh*xh only; NTERM=2: +wl*xh.
// OUT_PAIRED: 3 outputs bf16 h-paired; else fp32 planar.
// kscale: extra output scale on cv==1 (folds softmax scale into k).
// ---------------------------------------------------------------------------
template<int NC, int CVB, int INMODE, bool OUT_PAIRED, int NTERM>
__global__ __launch_bounds__(256)
void conv_mfma_kernel(const void* __restrict__ xin,
                      const unsigned* __restrict__ wfrag,
                      const float* __restrict__ b0, const float* __restrict__ b1,
                      const float* __restrict__ b2,
                      unsigned* __restrict__ o0, unsigned* __restrict__ o1,
                      unsigned* __restrict__ o2, float* __restrict__ of,
                      float kscale)
{
    constexpr int LC2 = 34, NPX = 18*34;                  // 612 pixels w/ halo
    __shared__ __align__(16) unsigned char xs[NPX*32];
    __shared__ unsigned rawv[(INMODE == 1) ? 16*10*34 : 1];

    const int tid = threadIdx.x;
    const int bx = blockIdx.x, by = blockIdx.y, bz = blockIdx.z;
    const int lane = tid & 63, wid = tid >> 6;
    const int g = lane >> 4, r = lane & 15;

    u32x4 wh[NC][5], wl[NC][5];
    #pragma unroll
    for (int cv = 0; cv < NC; ++cv)
        #pragma unroll
        for (int kg = 0; kg < 5; ++kg) {
            wh[cv][kg] = *(const u32x4*)(wfrag + (size_t)(((CVB+cv)*5 + kg)*64 + lane)*4);
            if constexpr (NTERM >= 2)
                wl[cv][kg] = *(const u32x4*)(wfrag + (size_t)(((4+CVB+cv)*5 + kg)*64 + lane)*4);
        }
    const float* bg[3] = {b0, b1, b2};
    f32x4 bias[NC];
    #pragma unroll
    for (int cv = 0; cv < NC; ++cv) bias[cv] = *(const f32x4*)(bg[cv] + 4*g);

    const int row0 = by*16 - 1, col0 = bx*32 - 1;

    if constexpr (INMODE == 1) {
        // Phase A: coalesced raw stage of hp-rows [8by-1 .. 8by+8] x 34 cols
        const unsigned* xb = (const unsigned*)xin + (size_t)bz*CC*(HH/2)*WW;
        const int hpbase = 8*by - 1;
        for (int idx = tid; idx < 16*10*34; idx += 256) {
            int c   = idx / 340;
            int rem = idx - c*340;
            int hpr = rem / 34;
            int wr  = rem - hpr*34;
            int hpg = hpbase + hpr; hpg = hpg < 0 ? 0 : (hpg > 127 ? 127 : hpg);
            int gcc = col0 + wr;    gcc = gcc < 0 ? 0 : (gcc > WW-1 ? WW-1 : gcc);
            rawv[idx] = xb[(size_t)c*(HH/2)*WW + (size_t)hpg*WW + gcc];
        }
        __syncthreads();
        // Phase B: per-pixel LDS reads + v_perm -> xs channel-last
        for (int idx = tid; idx < NPX; idx += 256) {
            int rr = idx / LC2, cc2 = idx - rr*LC2;
            int gr = row0 + rr;
            bool ok = (gr >= 0) & (gr < HH) & ((col0 + cc2) >= 0) & ((col0 + cc2) < WW);
            int grc = gr < 0 ? 0 : (gr > HH-1 ? HH-1 : gr);
            int hl  = (grc >> 1) - hpbase;        // in [0,9]
            const unsigned sel = (grc & 1) ? 0x07060302u : 0x05040100u;
            unsigned wv[16];
            #pragma unroll
            for (int c8 = 0; c8 < 16; ++c8)
                wv[c8] = ok ? rawv[c8*340 + hl*34 + cc2] : 0u;
            unsigned hi[8];
            #pragma unroll
            for (int p = 0; p < 8; ++p)
                hi[p] = __builtin_amdgcn_perm(wv[2*p+1], wv[2*p], sel);
            unsigned base = (unsigned)idx*32, m = ((unsigned)idx & 4) << 2;
            *(u32x4*)(xs + base + (( 0u) ^ m)) = (u32x4){hi[0], hi[1], hi[2], hi[3]};
            *(u32x4*)(xs + base + ((16u) ^ m)) = (u32x4){hi[4], hi[5], hi[6], hi[7]};
        }
    } else {
        for (int idx = tid; idx < NPX; idx += 256) {
            int rr = idx / LC2, cc2 = idx - rr*LC2;
            int gr = row0 + rr, gc = col0 + cc2;
            bool ok = (gr >= 0) & (gr < HH) & (gc >= 0) & (gc < WW);
            const unsigned* xb = (const unsigned*)xin + (size_t)bz*HH*WW*8;
            int grc = gr < 0 ? 0 : (gr > HH-1 ? HH-1 : gr);
            int gcc = gc < 0 ? 0 : (gc > WW-1 ? WW-1 : gc);
            const unsigned* px = xb + ((size_t)grc*WW + gcc)*8;
            u32x4 A = *(const u32x4*)(px);
            u32x4 Bv = *(const u32x4*)(px + 4);
            if (!ok) { A = (u32x4){0,0,0,0}; Bv = (u32x4){0,0,0,0}; }
            unsigned base = (unsigned)idx*32, m = ((unsigned)idx & 4) << 2;
            *(u32x4*)(xs + base + (( 0u) ^ m)) = A;
            *(u32x4*)(xs + base + ((16u) ^ m)) = Bv;
        }
    }
    __syncthreads();

    int pk_base[5];
    #pragma unroll
    for (int kg = 0; kg < 5; ++kg) {
        int tap = 2*kg + (g >> 1);
        if (tap > 8) tap = 8;
        pk_base[kg] = (tap/3)*LC2 + (tap%3) + r;
    }
    const unsigned sh = (unsigned)(g & 1) << 4;

    auto tile = [&](int hr, int wt, f32x4* acc) {
        const int tb = hr*LC2 + wt*16;
        #pragma unroll
        for (int kg = 0; kg < 5; ++kg) {
            int px = tb + pk_base[kg];
            unsigned b_ = (unsigned)px*32, m = ((unsigned)px & 4) << 2;
            u32x4 Bh = *(const u32x4*)(xs + b_ + (sh ^ m));
            #pragma unroll
            for (int cv = 0; cv < NC; ++cv) {
                acc[cv] = mfma16(wh[cv][kg], Bh, acc[cv]);
                if constexpr (NTERM >= 2)
                    acc[cv] = mfma16(wl[cv][kg], Bh, acc[cv]);
            }
        }
    };

    #pragma unroll 1
    for (int hp = 0; hp < 2; ++hp) {
        const int hrE = 4*wid + 2*hp;
        #pragma unroll 1
        for (int wt = 0; wt < 2; ++wt) {
            const int col = bx*32 + wt*16 + r;
            if constexpr (OUT_PAIRED) {
                f32x4 aE[NC];
                #pragma unroll
                for (int cv = 0; cv < NC; ++cv) aE[cv] = (f32x4){0.f,0.f,0.f,0.f};
                tile(hrE, wt, aE);
                unsigned Ep[NC][2];
                #pragma unroll
                for (int cv = 0; cv < NC; ++cv) {
                    const float sc = (cv == 1) ? kscale : 1.0f;
                    Ep[cv][0] = cvtpk((aE[cv][0] + bias[cv][0])*sc, (aE[cv][1] + bias[cv][1])*sc);
                    Ep[cv][1] = cvtpk((aE[cv][2] + bias[cv][2])*sc, (aE[cv][3] + bias[cv][3])*sc);
                }
                f32x4 aO[NC];
                #pragma unroll
                for (int cv = 0; cv < NC; ++cv) aO[cv] = (f32x4){0.f,0.f,0.f,0.f};
                tile(hrE + 1, wt, aO);
                const int hpix = by*8 + 2*wid + hp;
                #pragma unroll
                for (int cv = 0; cv < NC; ++cv) {
                    const float sc = (cv == 1) ? kscale : 1.0f;
                    unsigned Op0 = cvtpk((aO[cv][0] + bias[cv][0])*sc, (aO[cv][1] + bias[cv][1])*sc);
                    unsigned Op1 = cvtpk((aO[cv][2] + bias[cv][2])*sc, (aO[cv][3] + bias[cv][3])*sc);
                    unsigned wd[4] = {
                        __builtin_amdgcn_perm(Op0, Ep[cv][0], 0x05040100u),
                        __builtin_amdgcn_perm(Op0, Ep[cv][0], 0x07060302u),
                        __builtin_amdgcn_perm(Op1, Ep[cv][1], 0x05040100u),
                        __builtin_amdgcn_perm(Op1, Ep[cv][1], 0x07060302u) };
                    unsigned* op = (cv == 0) ? o0 : (cv == 1) ? o1 : o2;
                    #pragma unroll
                    for (int reg = 0; reg < 4; ++reg)
                        op[((size_t)(bz*CC + 4*g + reg)*(HH/2) + hpix)*WW + col] = wd[reg];
                }
            } else {
                #pragma unroll 1
                for (int e = 0; e < 2; ++e) {
                    f32x4 a0[1] = {(f32x4){0.f,0.f,0.f,0.f}};
                    tile(hrE + e, wt, a0);
                    const int h = by*16 + hrE + e;
                    #pragma unroll
                    for (int reg = 0; reg < 4; ++reg)
                        of[((size_t)(bz*CC + 4*g + reg)*HH + h)*WW + col] =
                            a0[0][reg] + bias[0][reg];
                }
            }
        }
    }
}

// ---------------------------------------------------------------------------
// bf16 MFMA flash attention (best-measured config): swapped-operand +
// permlane P-transpose, one-shot 64 KiB K/V stage, qi=4, ones-row MFMA for l.
// Output written as h-paired bf16 u32 [c][h/2][w] (feeds conv1 directly).
// ---------------------------------------------------------------------------
__global__ __launch_bounds__(512)
void attn_mfma_kernel(const unsigned* __restrict__ q,
                      const unsigned* __restrict__ k,
                      const unsigned* __restrict__ v,
                      unsigned* __restrict__ apk)
{
    __shared__ __align__(16) unsigned char Kl[WW*DD*2];      // 32 KiB
    __shared__ __align__(16) unsigned char Vl[DD*WW*2];      // 32 KiB

    const int s  = blockIdx.x;
    const int n  = s & (NHD-1);
    const int bc = s >> 3;
    const int pbase = (bc*(HH/2) + n*(DD/2)) * WW;           // u32 elements
    const unsigned* qg = q + pbase;
    const unsigned* kg = k + pbase;
    const unsigned* vg = v + pbase;
    unsigned* ag = apk + pbase;

    const int tid = threadIdx.x;

    // --- stage K: thread t -> key = t; 16 d-pair words, native layout ---
    {
        const int key = tid;
        unsigned pk[16];
        #pragma unroll
        for (int dp = 0; dp < 16; ++dp) pk[dp] = kg[(size_t)dp*WW + key];
        #pragma unroll
        for (int j = 0; j < 4; ++j) {
            unsigned off = (unsigned)(key*64 + j*16) ^ ((unsigned)(key&7) << 4);
            *(u32x4*)(Kl + off) = (u32x4){pk[4*j], pk[4*j+1], pk[4*j+2], pk[4*j+3]};
        }
    }
    // --- stage V: unzip d-pairs -> Vl[d][key-slots] via v_perm.
    // Slot order per 16-key chunk applies quad perm [0,2,1,3]: the two b128
    // writes carry word sets {P0,P1,P4,P5} and {P2,P3,P6,P7}. ---
    {
        const int dp = tid >> 5;                  // 0..15
        const int k0 = (tid & 31) * 16;
        unsigned rowE[8], rowO[8];
        #pragma unroll
        for (int j = 0; j < 4; ++j) {
            u32x4 U = *(const u32x4*)(vg + (size_t)dp*WW + k0 + 4*j);
            rowE[2*j  ] = __builtin_amdgcn_perm(U[1], U[0], 0x05040100u);
            rowE[2*j+1] = __builtin_amdgcn_perm(U[3], U[2], 0x05040100u);
            rowO[2*j  ] = __builtin_amdgcn_perm(U[1], U[0], 0x07060302u);
            rowO[2*j+1] = __builtin_amdgcn_perm(U[3], U[2], 0x07060302u);
        }
        const int d0 = 2*dp, d1 = 2*dp + 1;
        const unsigned bE = (unsigned)(d0*1024 + k0*2);
        const unsigned bO = (unsigned)(d1*1024 + k0*2);
        const unsigned mE = ((unsigned)d0 & 7u) << 4;
        const unsigned mO = ((unsigned)d1 & 7u) << 4;
        *(u32x4*)(Vl + ((bE     ) ^ mE)) = (u32x4){rowE[0], rowE[1], rowE[4], rowE[5]};
        *(u32x4*)(Vl + ((bE + 16) ^ mE)) = (u32x4){rowE[2], rowE[3], rowE[6], rowE[7]};
        *(u32x4*)(Vl + ((bO     ) ^ mO)) = (u32x4){rowO[0], rowO[1], rowO[4], rowO[5]};
        *(u32x4*)(Vl + ((bO + 16) ^ mO)) = (u32x4){rowO[2], rowO[3], rowO[6], rowO[7]};
    }

    const int wid  = tid >> 6;
    const int lane = tid & 63;
    const int g = lane >> 4;
    const int r = lane & 15;
    const int w0 = wid * 64;

    // --- per-wave Q B-fragments (col = query r, k = d octet 8g..8g+7) ---
    u32x4 qf[4];
    #pragma unroll
    for (int rf = 0; rf < 4; ++rf) {
        const int row = w0 + rf*16 + r;
        unsigned pq[4];
        #pragma unroll
        for (int jj = 0; jj < 4; ++jj)
            pq[jj] = qg[(size_t)(4*g + jj)*WW + row];
        qf[rf] = (u32x4){pq[0], pq[1], pq[2], pq[3]};
    }

    __syncthreads();   // K/V staged

    // ones A-fragment (row 0 = 1.0) for l = sum_k P^T
    const u32x4 vones = (r == 0)
        ? (u32x4){0x3F803F80u, 0x3F803F80u, 0x3F803F80u, 0x3F803F80u}
        : (u32x4){0u, 0u, 0u, 0u};

    f32x4 oacc[4][2];
    f32x4 lacc[4];
    #pragma unroll
    for (int qi = 0; qi < 4; ++qi) {
        oacc[qi][0] = (f32x4){0.f,0.f,0.f,0.f};
        oacc[qi][1] = (f32x4){0.f,0.f,0.f,0.f};
        lacc[qi]    = (f32x4){0.f,0.f,0.f,0.f};
    }

    #pragma unroll 1
    for (int j0 = 0; j0 < WW; j0 += 32) {
        u32x4 kf[2];
        #pragma unroll
        for (int cf = 0; cf < 2; ++cf) {
            const int key = j0 + cf*16 + r;
            unsigned off = (unsigned)(key*64 + g*16) ^ ((unsigned)(key&7) << 4);
            kf[cf] = *(const u32x4*)(Kl + off);
        }
        u32x4 vf[2];
        #pragma unroll
        for (int cfd = 0; cfd < 2; ++cfd) {
            const int d = r + 16*cfd;
            unsigned off = (unsigned)(d*1024 + (j0 + 8*g)*2) ^ ((unsigned)(d&7) << 4);
            vf[cfd] = *(const u32x4*)(Vl + off);
        }

        f32x4 sacc[4][2];
        #pragma unroll
        for (int qi = 0; qi < 4; ++qi) {
            sacc[qi][0] = mfma16(kf[0], qf[qi], (f32x4){0.f,0.f,0.f,0.f});
            sacc[qi][1] = mfma16(kf[1], qf[qi], (f32x4){0.f,0.f,0.f,0.f});
        }

        #pragma unroll
        for (int qi = 0; qi < 4; ++qi) {
            float p0 = __builtin_amdgcn_exp2f(sacc[qi][0][0]);
            float p1 = __builtin_amdgcn_exp2f(sacc[qi][0][1]);
            float p2 = __builtin_amdgcn_exp2f(sacc[qi][0][2]);
            float p3 = __builtin_amdgcn_exp2f(sacc[qi][0][3]);
            float p4 = __builtin_amdgcn_exp2f(sacc[qi][1][0]);
            float p5 = __builtin_amdgcn_exp2f(sacc[qi][1][1]);
            float p6 = __builtin_amdgcn_exp2f(sacc[qi][1][2]);
            float p7 = __builtin_amdgcn_exp2f(sacc[qi][1][3]);
            unsigned Aw = cvtpk(p0, p1);   // keys (4g,   4g+1)
            unsigned Bw = cvtpk(p2, p3);   // keys (4g+2, 4g+3)
            unsigned Cw = cvtpk(p4, p5);   // keys (16+4g, 16+4g+1)
            unsigned Dw = cvtpk(p6, p7);   // keys (16+4g+2, 16+4g+3)
            i32x2 w02 = __builtin_amdgcn_permlane32_swap((int)Aw, (int)Cw, false, false);
            i32x2 w13 = __builtin_amdgcn_permlane32_swap((int)Bw, (int)Dw, false, false);
            u32x4 pa = (u32x4){ (unsigned)w02[0], (unsigned)w13[0],
                                (unsigned)w02[1], (unsigned)w13[1] };
            oacc[qi][0] = mfma16(vf[0], pa, oacc[qi][0]);
            oacc[qi][1] = mfma16(vf[1], pa, oacc[qi][1]);
            lacc[qi]    = mfma16(vones, pa, lacc[qi]);
        }
    }

    // normalize + store h-paired bf16: regs 0/1 and 2/3 are consecutive d.
    #pragma unroll
    for (int qi = 0; qi < 4; ++qi) {
        float l = __shfl(lacc[qi][0], r);     // lane r (g=0,reg0) holds col-r sum
        float inv = 1.0f / l;
        const int qcol = w0 + qi*16 + r;
        #pragma unroll
        for (int cfd = 0; cfd < 2; ++cfd) {
            const int dpair = 8*cfd + 2*g;    // d = 16cfd + 4g + reg
            unsigned P0 = cvtpk(oacc[qi][cfd][0]*inv, oacc[qi][cfd][1]*inv);
            unsigned P1 = cvtpk(oacc[qi][cfd][2]*inv, oacc[qi][cfd][3]*inv);
            ag[(size_t)(dpair    )*WW + qcol] = P0;
            ag[(size_t)(dpair + 1)*WW + qcol] = P1;
        }
    }
}

extern "C" void kernel_launch(void* const* d_in, const int* in_sizes, int n_in,
                              void* d_out, int out_size, void* d_ws, size_t ws_size,
                              hipStream_t stream) {
    (void)in_sizes; (void)n_in; (void)out_size; (void)ws_size;
    const float* x  = (const float*)d_in[0];
    const float* wq = (const float*)d_in[1];
    const float* bq = (const float*)d_in[2];
    const float* wk = (const float*)d_in[3];
    const float* bk = (const float*)d_in[4];
    const float* wv = (const float*)d_in[5];
    const float* bv = (const float*)d_in[6];
    const float* wo = (const float*)d_in[7];
    const float* bo = (const float*)d_in[8];
    float* out = (float*)d_out;

    const float SC = 0.0625f * 1.44269504088896340736f;  // 1/sqrt(256) * log2(e)

    const size_t S = (size_t)BB*CC*HH*WW;          // 8388608
    unsigned* apk  = (unsigned*)d_ws;              // S/2 u32 (h-paired bf16)
    unsigned* qpk  = apk + S/2;
    unsigned* kpk  = qpk + S/2;
    unsigned* vpk  = kpk + S/2;
    unsigned* xcl  = vpk + S/2;                    // S/2 u32 (channel-last bf16)
    unsigned* wfrag = xcl + S/2;                   // 10240 u32

    // xpack (z<4) + wsetup (z==4 plane, 4 active blocks)
    xpack_kernel<<<dim3(WW/64, HH/8, BB+1), 256, 0, stream>>>(
        x, xcl, wq, wk, wv, wo, wfrag);
    dim3 cgrid(WW/32, HH/16, BB);                  // (16,16,4)
    conv_mfma_kernel<3, 0, 2, true, 1><<<cgrid, 256, 0, stream>>>(
        xcl, wfrag, bq, bk, bv, qpk, kpk, vpk, nullptr, SC);
    attn_mfma_kernel<<<dim3(512), 512, 0, stream>>>(qpk, kpk, vpk, apk);
    conv_mfma_kernel<1, 3, 1, false, 2><<<cgrid, 256, 0, stream>>>(
        apk, wfrag, bo, bo, bo, nullptr, nullptr, nullptr, out, 1.0f);
}